// Round 3
// baseline (513.238 us; speedup 1.0000x reference)
//
#include <hip/hip_runtime.h>

// GraphRelativeError: rel = |pred-target|/(|target|+0.1); per-graph mean over
// SORTED segments (G=1024, ~16384 elems each); out = mean(graph_means)*1e4.
//
// R2 design (resubmitted — R2 bench never acquired a GPU):
//  - gre_starts: 1025 parallel lower_bound searches -> starts[g] (one tiny
//    kernel). Removes ALL batch searching/streaming from the hot kernel and
//    gives counts analytically (starts[g+1]-starts[g]).
//  - gre_main: pure stream-accumulate of pred/target (float4), split point is
//    a single load starts[b1]. Per-wave shuffle reduce -> <=2 atomics/wave.
//    Finalize fused via last-block ticket (device-scope) -> one fewer node.
//  - Traffic: 128 MiB (pred+target) only. Floor ~21 us @ 6.3 TB/s.

#define EPSILON_F 0.1f
#define SCALE_F 10000.0f

constexpr int BLOCK = 256;
constexpr int EPB = 8192;              // elements per block
constexpr int IT = EPB / (BLOCK * 4);  // 8 float4 iters per thread
constexpr int G_CONST = 1024;

// batch storage may be int32 (jax default) or int64 (x64 mode). Probe: batch
// is sorted with max = G-1 != 0, so int32-view element [n-1] is 0 iff int64.
__device__ __forceinline__ int load_batch(const int* __restrict__ b32,
                                          long long idx, bool is64) {
  return b32[is64 ? (idx << 1) : idx];
}

__global__ __launch_bounds__(BLOCK)
void gre_starts(const int* __restrict__ batch32, int n, int g,
                int* __restrict__ starts) {
  const int t = blockIdx.x * BLOCK + threadIdx.x;
  if (t > g) return;
  if (t == 0) { starts[0] = 0; return; }
  if (t == g) { starts[g] = n; return; }
  const bool is64 = (batch32[n - 1] == 0);
  int lo = 0, hi = n;  // first index with batch[i] >= t
  while (lo < hi) {
    int mid = (lo + hi) >> 1;
    if (load_batch(batch32, mid, is64) < t) lo = mid + 1; else hi = mid;
  }
  starts[t] = lo;
}

__global__ __launch_bounds__(BLOCK)
void gre_main(const float* __restrict__ pred, const float* __restrict__ target,
              const int* __restrict__ batch32, int n, int g,
              const int* __restrict__ starts, float* __restrict__ sums,
              unsigned int* __restrict__ done, float* __restrict__ out) {
  const int tid = threadIdx.x;
  const long long s = (long long)blockIdx.x * EPB;
  long long e = s + EPB;
  if (e > n) e = n;
  const bool is64 = (batch32[n - 1] == 0);
  const int b0 = load_batch(batch32, s, is64);
  const int b1 = load_batch(batch32, e - 1, is64);

  float A = 0.f, B = 0.f;

  if (b1 == b0) {
    // single-segment block (~50%): pure stream-accumulate, dual accumulators
    float Bx = 0.f, By = 0.f;
    #pragma unroll
    for (int it = 0; it < IT; ++it) {
      long long i4 = s + (long long)(it * BLOCK + tid) * 4;
      if (i4 + 4 <= e) {
        float4 pv = *reinterpret_cast<const float4*>(pred + i4);
        float4 tv = *reinterpret_cast<const float4*>(target + i4);
        Bx += fabsf(pv.x - tv.x) / (fabsf(tv.x) + EPSILON_F);
        By += fabsf(pv.y - tv.y) / (fabsf(tv.y) + EPSILON_F);
        Bx += fabsf(pv.z - tv.z) / (fabsf(tv.z) + EPSILON_F);
        By += fabsf(pv.w - tv.w) / (fabsf(tv.w) + EPSILON_F);
      } else {
        for (int j = 0; j < 4; ++j) {
          long long i = i4 + j;
          if (i < e)
            Bx += fabsf(pred[i] - target[i]) / (fabsf(target[i]) + EPSILON_F);
        }
      }
    }
    B = Bx + By;
  } else if (b1 == b0 + 1) {
    // one boundary: split point is a single load (no search)
    const long long p = (long long)starts[b1];
    #pragma unroll
    for (int it = 0; it < IT; ++it) {
      long long i4 = s + (long long)(it * BLOCK + tid) * 4;
      if (i4 + 4 <= e) {
        float4 pv = *reinterpret_cast<const float4*>(pred + i4);
        float4 tv = *reinterpret_cast<const float4*>(target + i4);
        float r0 = fabsf(pv.x - tv.x) / (fabsf(tv.x) + EPSILON_F);
        float r1 = fabsf(pv.y - tv.y) / (fabsf(tv.y) + EPSILON_F);
        float r2 = fabsf(pv.z - tv.z) / (fabsf(tv.z) + EPSILON_F);
        float r3 = fabsf(pv.w - tv.w) / (fabsf(tv.w) + EPSILON_F);
        A += (i4 + 0 < p) ? r0 : 0.f;  B += (i4 + 0 < p) ? 0.f : r0;
        A += (i4 + 1 < p) ? r1 : 0.f;  B += (i4 + 1 < p) ? 0.f : r1;
        A += (i4 + 2 < p) ? r2 : 0.f;  B += (i4 + 2 < p) ? 0.f : r2;
        A += (i4 + 3 < p) ? r3 : 0.f;  B += (i4 + 3 < p) ? 0.f : r3;
      } else {
        for (int j = 0; j < 4; ++j) {
          long long i = i4 + j;
          if (i < e) {
            float r = fabsf(pred[i] - target[i]) / (fabsf(target[i]) + EPSILON_F);
            if (i < p) A += r; else B += r;
          }
        }
      }
    }
  } else {
    // generic fallback (>=2 boundaries in 8192 elems: impossible for this
    // data, kept for correctness): per-element binning
    for (int it = 0; it < IT; ++it) {
      long long i4 = s + (long long)(it * BLOCK + tid) * 4;
      for (int j = 0; j < 4; ++j) {
        long long i = i4 + j;
        if (i < e) {
          int gi = load_batch(batch32, i, is64);
          float r = fabsf(pred[i] - target[i]) / (fabsf(target[i]) + EPSILON_F);
          atomicAdd(&sums[gi], r);
        }
      }
    }
  }

  // per-wave reduction -> <=2 global atomics per wave
  #pragma unroll
  for (int off = 32; off > 0; off >>= 1) {
    A += __shfl_down(A, off, 64);
    B += __shfl_down(B, off, 64);
  }
  if ((tid & 63) == 0) {
    atomicAdd(&sums[b1], B);
    if (b1 != b0) atomicAdd(&sums[b0], A);
  }

  // ----- fused finalize: last block reduces mean(sums[g]/count[g]) -----
  __syncthreads();
  __threadfence();  // make this block's atomics device-visible
  __shared__ unsigned int rank_s;
  if (tid == 0)
    rank_s = __hip_atomic_fetch_add(done, 1u, __ATOMIC_ACQ_REL,
                                    __HIP_MEMORY_SCOPE_AGENT);
  __syncthreads();
  if (rank_s == gridDim.x - 1) {
    __threadfence();  // acquire all blocks' sums
    float v = 0.f;
    for (int i = tid; i < g; i += BLOCK) {
      float sv = __hip_atomic_load(&sums[i], __ATOMIC_RELAXED,
                                   __HIP_MEMORY_SCOPE_AGENT);
      int c = starts[i + 1] - starts[i];
      v += sv / (float)c;
    }
    #pragma unroll
    for (int off = 32; off > 0; off >>= 1) v += __shfl_down(v, off, 64);
    __shared__ float wsum[BLOCK / 64];
    if ((tid & 63) == 0) wsum[tid >> 6] = v;
    __syncthreads();
    if (tid == 0) {
      float t = 0.f;
      #pragma unroll
      for (int w = 0; w < BLOCK / 64; ++w) t += wsum[w];
      out[0] = (t / (float)g) * SCALE_F;
    }
  }
}

extern "C" void kernel_launch(void* const* d_in, const int* in_sizes, int n_in,
                              void* d_out, int out_size, void* d_ws, size_t ws_size,
                              hipStream_t stream) {
  const float* pred   = (const float*)d_in[0];
  const float* target = (const float*)d_in[1];
  const int*   batch  = (const int*)d_in[2];  // int32 or int64, probed on device
  const int n = in_sizes[0];
  const int g = G_CONST;

  // ws layout: sums[1024] f32 | starts[1025->1056] i32 | done u32
  float* sums = (float*)d_ws;
  int* starts = (int*)((char*)d_ws + 4096);
  unsigned int* done = (unsigned int*)((char*)d_ws + 4096 + 1056 * 4);
  hipMemsetAsync(d_ws, 0, 4096 + 1056 * 4 + 64, stream);  // zero sums+done

  gre_starts<<<(g + BLOCK) / BLOCK, BLOCK, 0, stream>>>(batch, n, g, starts);

  const int nblocks = (n + EPB - 1) / EPB;
  gre_main<<<nblocks, BLOCK, 0, stream>>>(pred, target, batch, n, g, starts,
                                          sums, done, (float*)d_out);
}

// Round 6
// 229.858 us; speedup vs baseline: 2.2328x; 2.2328x over previous
//
#include <hip/hip_runtime.h>

// GraphRelativeError: rel = |pred-target|/(|target|+0.1); per-graph mean over
// SORTED segments (G=1024, ~16384 elems each); out = mean(graph_means)*1e4.
//
// R3 (resubmitted — R4/R5 benches never acquired a GPU):
// R2's fused last-block finalize REMOVED — its per-block __threadfence()
// + AGENT acq_rel atomic forced L2 writeback/invalidate on every one of 2048
// blocks (per-XCD L2s non-coherent) -> 345 us, 2.7% VALUBusy. Finalize is a
// separate 1-block kernel again; sums zeroing folded into gre_starts (no
// memset node). Main kernel: pure float4 stream-accumulate, split point from
// precomputed starts[], plain (relaxed) atomicAdd only.

#define EPSILON_F 0.1f
#define SCALE_F 10000.0f

constexpr int BLOCK = 256;
constexpr int EPB = 8192;              // elements per block
constexpr int IT = EPB / (BLOCK * 4);  // 8 float4 iters per thread
constexpr int G_CONST = 1024;

// batch storage may be int32 (jax default) or int64 (x64 mode). Probe: batch
// is sorted with max = G-1 != 0, so int32-view element [n-1] is 0 iff int64.
__device__ __forceinline__ int load_batch(const int* __restrict__ b32,
                                          long long idx, bool is64) {
  return b32[is64 ? (idx << 1) : idx];
}

// Also zeroes sums[] so no separate memset node is needed.
__global__ __launch_bounds__(BLOCK)
void gre_starts(const int* __restrict__ batch32, int n, int g,
                int* __restrict__ starts, float* __restrict__ sums) {
  const int t = blockIdx.x * BLOCK + threadIdx.x;
  if (t < g) sums[t] = 0.f;
  if (t > g) return;
  if (t == 0) { starts[0] = 0; return; }
  if (t == g) { starts[g] = n; return; }
  const bool is64 = (batch32[n - 1] == 0);
  int lo = 0, hi = n;  // first index with batch[i] >= t
  while (lo < hi) {
    int mid = (lo + hi) >> 1;
    if (load_batch(batch32, mid, is64) < t) lo = mid + 1; else hi = mid;
  }
  starts[t] = lo;
}

__global__ __launch_bounds__(BLOCK)
void gre_main(const float* __restrict__ pred, const float* __restrict__ target,
              const int* __restrict__ batch32, int n,
              const int* __restrict__ starts, float* __restrict__ sums) {
  const int tid = threadIdx.x;
  const long long s = (long long)blockIdx.x * EPB;
  long long e = s + EPB;
  if (e > n) e = n;
  const bool is64 = (batch32[n - 1] == 0);
  const int b0 = load_batch(batch32, s, is64);
  const int b1 = load_batch(batch32, e - 1, is64);

  float A = 0.f, B = 0.f;

  if (b1 == b0) {
    // single-segment block (~50%): pure stream-accumulate, dual accumulators
    float Bx = 0.f, By = 0.f;
    #pragma unroll
    for (int it = 0; it < IT; ++it) {
      long long i4 = s + (long long)(it * BLOCK + tid) * 4;
      if (i4 + 4 <= e) {
        float4 pv = *reinterpret_cast<const float4*>(pred + i4);
        float4 tv = *reinterpret_cast<const float4*>(target + i4);
        Bx += fabsf(pv.x - tv.x) / (fabsf(tv.x) + EPSILON_F);
        By += fabsf(pv.y - tv.y) / (fabsf(tv.y) + EPSILON_F);
        Bx += fabsf(pv.z - tv.z) / (fabsf(tv.z) + EPSILON_F);
        By += fabsf(pv.w - tv.w) / (fabsf(tv.w) + EPSILON_F);
      } else {
        for (int j = 0; j < 4; ++j) {
          long long i = i4 + j;
          if (i < e)
            Bx += fabsf(pred[i] - target[i]) / (fabsf(target[i]) + EPSILON_F);
        }
      }
    }
    B = Bx + By;
  } else if (b1 == b0 + 1) {
    // one boundary: split point is a single broadcast load (no search)
    const long long p = (long long)starts[b1];
    #pragma unroll
    for (int it = 0; it < IT; ++it) {
      long long i4 = s + (long long)(it * BLOCK + tid) * 4;
      if (i4 + 4 <= e) {
        float4 pv = *reinterpret_cast<const float4*>(pred + i4);
        float4 tv = *reinterpret_cast<const float4*>(target + i4);
        float r0 = fabsf(pv.x - tv.x) / (fabsf(tv.x) + EPSILON_F);
        float r1 = fabsf(pv.y - tv.y) / (fabsf(tv.y) + EPSILON_F);
        float r2 = fabsf(pv.z - tv.z) / (fabsf(tv.z) + EPSILON_F);
        float r3 = fabsf(pv.w - tv.w) / (fabsf(tv.w) + EPSILON_F);
        A += (i4 + 0 < p) ? r0 : 0.f;  B += (i4 + 0 < p) ? 0.f : r0;
        A += (i4 + 1 < p) ? r1 : 0.f;  B += (i4 + 1 < p) ? 0.f : r1;
        A += (i4 + 2 < p) ? r2 : 0.f;  B += (i4 + 2 < p) ? 0.f : r2;
        A += (i4 + 3 < p) ? r3 : 0.f;  B += (i4 + 3 < p) ? 0.f : r3;
      } else {
        for (int j = 0; j < 4; ++j) {
          long long i = i4 + j;
          if (i < e) {
            float r = fabsf(pred[i] - target[i]) / (fabsf(target[i]) + EPSILON_F);
            if (i < p) A += r; else B += r;
          }
        }
      }
    }
  } else {
    // generic fallback (>=2 boundaries in 8192 elems: impossible for this
    // data, kept for correctness): per-element binning
    for (int it = 0; it < IT; ++it) {
      long long i4 = s + (long long)(it * BLOCK + tid) * 4;
      for (int j = 0; j < 4; ++j) {
        long long i = i4 + j;
        if (i < e) {
          int gi = load_batch(batch32, i, is64);
          float r = fabsf(pred[i] - target[i]) / (fabsf(target[i]) + EPSILON_F);
          atomicAdd(&sums[gi], r);
        }
      }
    }
  }

  // per-wave reduction -> <=2 relaxed global atomics per wave (no fences!)
  #pragma unroll
  for (int off = 32; off > 0; off >>= 1) {
    A += __shfl_down(A, off, 64);
    B += __shfl_down(B, off, 64);
  }
  if ((tid & 63) == 0) {
    atomicAdd(&sums[b1], B);
    if (b1 != b0) atomicAdd(&sums[b0], A);
  }
}

__global__ __launch_bounds__(BLOCK)
void gre_final(const float* __restrict__ sums, const int* __restrict__ starts,
               float* __restrict__ out, int g) {
  const int tid = threadIdx.x;
  float v = 0.f;
  for (int i = tid; i < g; i += BLOCK)
    v += sums[i] / (float)(starts[i + 1] - starts[i]);
  #pragma unroll
  for (int off = 32; off > 0; off >>= 1) v += __shfl_down(v, off, 64);
  __shared__ float wsum[BLOCK / 64];
  if ((tid & 63) == 0) wsum[tid >> 6] = v;
  __syncthreads();
  if (tid == 0) {
    float t = 0.f;
    #pragma unroll
    for (int w = 0; w < BLOCK / 64; ++w) t += wsum[w];
    out[0] = (t / (float)g) * SCALE_F;
  }
}

extern "C" void kernel_launch(void* const* d_in, const int* in_sizes, int n_in,
                              void* d_out, int out_size, void* d_ws, size_t ws_size,
                              hipStream_t stream) {
  const float* pred   = (const float*)d_in[0];
  const float* target = (const float*)d_in[1];
  const int*   batch  = (const int*)d_in[2];  // int32 or int64, probed on device
  const int n = in_sizes[0];
  const int g = G_CONST;

  // ws layout: sums[1024] f32 | starts[1025] i32
  float* sums = (float*)d_ws;
  int* starts = (int*)((char*)d_ws + 4096);

  gre_starts<<<(g + BLOCK) / BLOCK, BLOCK, 0, stream>>>(batch, n, g, starts,
                                                        sums);
  const int nblocks = (n + EPB - 1) / EPB;
  gre_main<<<nblocks, BLOCK, 0, stream>>>(pred, target, batch, n, starts, sums);
  gre_final<<<1, BLOCK, 0, stream>>>(sums, starts, (float*)d_out, g);
}

// Round 8
// 226.640 us; speedup vs baseline: 2.2645x; 1.0142x over previous
//
#include <hip/hip_runtime.h>

// GraphRelativeError: rel = |pred-target|/(|target|+0.1); per-graph mean over
// SORTED segments (G=1024, ~16384 elems each); out = mean(graph_means)*1e4.
//
// R7 (resubmitted — R7 bench never acquired a GPU):
// R3/R6 was latency-bound, not BW-bound (VGPR=24 -> only ~2 loads in flight
// per wave; VALUBusy 15%, HBM 16%). Restructure: EPB=4096, IT=4, issue ALL
// 8 float4 loads (pv[4]+tv[4]) back-to-back BEFORE consuming -> 8 KB in
// flight per wave, then compute rel in-place (VGPR target <=64 to keep 32
// waves/CU). starts[] hoist, relaxed atomics, separate finalize unchanged.

#define EPSILON_F 0.1f
#define SCALE_F 10000.0f

constexpr int BLOCK = 256;
constexpr int EPB = 4096;              // elements per block
constexpr int IT = EPB / (BLOCK * 4);  // 4 float4 iters per thread
constexpr int G_CONST = 1024;

// batch storage may be int32 (jax default) or int64 (x64 mode). Probe: batch
// is sorted with max = G-1 != 0, so int32-view element [n-1] is 0 iff int64.
__device__ __forceinline__ int load_batch(const int* __restrict__ b32,
                                          long long idx, bool is64) {
  return b32[is64 ? (idx << 1) : idx];
}

// Also zeroes sums[] so no separate memset node is needed.
__global__ __launch_bounds__(BLOCK)
void gre_starts(const int* __restrict__ batch32, int n, int g,
                int* __restrict__ starts, float* __restrict__ sums) {
  const int t = blockIdx.x * BLOCK + threadIdx.x;
  if (t < g) sums[t] = 0.f;
  if (t > g) return;
  if (t == 0) { starts[0] = 0; return; }
  if (t == g) { starts[g] = n; return; }
  const bool is64 = (batch32[n - 1] == 0);
  int lo = 0, hi = n;  // first index with batch[i] >= t
  while (lo < hi) {
    int mid = (lo + hi) >> 1;
    if (load_batch(batch32, mid, is64) < t) lo = mid + 1; else hi = mid;
  }
  starts[t] = lo;
}

__global__ __launch_bounds__(BLOCK)
void gre_main(const float* __restrict__ pred, const float* __restrict__ target,
              const int* __restrict__ batch32, int n,
              const int* __restrict__ starts, float* __restrict__ sums) {
  const int tid = threadIdx.x;
  const long long s = (long long)blockIdx.x * EPB;
  long long e = s + EPB;
  if (e > n) e = n;
  const bool is64 = (batch32[n - 1] == 0);
  const int b0 = load_batch(batch32, s, is64);
  const int b1 = load_batch(batch32, e - 1, is64);

  // ---- Load phase: issue ALL 8 float4 loads before any consumption ----
  float4 pv[IT], tv[IT];
  const bool full = (s + EPB <= (long long)n);
  if (full) {
    #pragma unroll
    for (int it = 0; it < IT; ++it) {
      const long long i4 = s + (long long)(it * BLOCK + tid) * 4;
      pv[it] = *reinterpret_cast<const float4*>(pred + i4);
      tv[it] = *reinterpret_cast<const float4*>(target + i4);
    }
  } else {
    #pragma unroll
    for (int it = 0; it < IT; ++it) {
      const long long i4 = s + (long long)(it * BLOCK + tid) * 4;
      float p[4] = {0.f, 0.f, 0.f, 0.f}, t[4] = {0.f, 0.f, 0.f, 0.f};
      #pragma unroll
      for (int j = 0; j < 4; ++j) {
        if (i4 + j < e) { p[j] = pred[i4 + j]; t[j] = target[i4 + j]; }
      }
      pv[it] = make_float4(p[0], p[1], p[2], p[3]);
      tv[it] = make_float4(t[0], t[1], t[2], t[3]);
      // zero-fill => rel = 0/(0+eps) = 0: harmless to any bin
    }
  }

  // ---- Compute rel in-place (overwrite pv -> saves VGPRs) ----
  #pragma unroll
  for (int it = 0; it < IT; ++it) {
    pv[it].x = fabsf(pv[it].x - tv[it].x) / (fabsf(tv[it].x) + EPSILON_F);
    pv[it].y = fabsf(pv[it].y - tv[it].y) / (fabsf(tv[it].y) + EPSILON_F);
    pv[it].z = fabsf(pv[it].z - tv[it].z) / (fabsf(tv[it].z) + EPSILON_F);
    pv[it].w = fabsf(pv[it].w - tv[it].w) / (fabsf(tv[it].w) + EPSILON_F);
  }

  // ---- Binning ----
  float A = 0.f, B = 0.f;
  if (b1 == b0) {
    float Bx = 0.f, By = 0.f;
    #pragma unroll
    for (int it = 0; it < IT; ++it) {
      Bx += pv[it].x + pv[it].z;
      By += pv[it].y + pv[it].w;
    }
    B = Bx + By;
  } else if (b1 == b0 + 1) {
    const long long p = (long long)starts[b1];  // one broadcast load
    #pragma unroll
    for (int it = 0; it < IT; ++it) {
      const long long i4 = s + (long long)(it * BLOCK + tid) * 4;
      A += (i4 + 0 < p) ? pv[it].x : 0.f;  B += (i4 + 0 < p) ? 0.f : pv[it].x;
      A += (i4 + 1 < p) ? pv[it].y : 0.f;  B += (i4 + 1 < p) ? 0.f : pv[it].y;
      A += (i4 + 2 < p) ? pv[it].z : 0.f;  B += (i4 + 2 < p) ? 0.f : pv[it].z;
      A += (i4 + 3 < p) ? pv[it].w : 0.f;  B += (i4 + 3 < p) ? 0.f : pv[it].w;
    }
  } else {
    // generic fallback (>=2 boundaries in 4096 elems: impossible for this
    // data, kept for correctness): per-element binning from registers
    #pragma unroll
    for (int it = 0; it < IT; ++it) {
      const long long i4 = s + (long long)(it * BLOCK + tid) * 4;
      const float rr[4] = {pv[it].x, pv[it].y, pv[it].z, pv[it].w};
      for (int j = 0; j < 4; ++j) {
        const long long i = i4 + j;
        if (i < e) {
          int gi = load_batch(batch32, i, is64);
          atomicAdd(&sums[gi], rr[j]);
        }
      }
    }
  }

  // per-wave reduction -> <=2 relaxed global atomics per wave (no fences!)
  #pragma unroll
  for (int off = 32; off > 0; off >>= 1) {
    A += __shfl_down(A, off, 64);
    B += __shfl_down(B, off, 64);
  }
  if ((tid & 63) == 0) {
    atomicAdd(&sums[b1], B);
    if (b1 != b0) atomicAdd(&sums[b0], A);
  }
}

__global__ __launch_bounds__(BLOCK)
void gre_final(const float* __restrict__ sums, const int* __restrict__ starts,
               float* __restrict__ out, int g) {
  const int tid = threadIdx.x;
  float v = 0.f;
  for (int i = tid; i < g; i += BLOCK)
    v += sums[i] / (float)(starts[i + 1] - starts[i]);
  #pragma unroll
  for (int off = 32; off > 0; off >>= 1) v += __shfl_down(v, off, 64);
  __shared__ float wsum[BLOCK / 64];
  if ((tid & 63) == 0) wsum[tid >> 6] = v;
  __syncthreads();
  if (tid == 0) {
    float t = 0.f;
    #pragma unroll
    for (int w = 0; w < BLOCK / 64; ++w) t += wsum[w];
    out[0] = (t / (float)g) * SCALE_F;
  }
}

extern "C" void kernel_launch(void* const* d_in, const int* in_sizes, int n_in,
                              void* d_out, int out_size, void* d_ws, size_t ws_size,
                              hipStream_t stream) {
  const float* pred   = (const float*)d_in[0];
  const float* target = (const float*)d_in[1];
  const int*   batch  = (const int*)d_in[2];  // int32 or int64, probed on device
  const int n = in_sizes[0];
  const int g = G_CONST;

  // ws layout: sums[1024] f32 | starts[1025] i32
  float* sums = (float*)d_ws;
  int* starts = (int*)((char*)d_ws + 4096);

  gre_starts<<<(g + BLOCK) / BLOCK, BLOCK, 0, stream>>>(batch, n, g, starts,
                                                        sums);
  const int nblocks = (n + EPB - 1) / EPB;
  gre_main<<<nblocks, BLOCK, 0, stream>>>(pred, target, batch, n, starts, sums);
  gre_final<<<1, BLOCK, 0, stream>>>(sums, starts, (float*)d_out, g);
}

// Round 12
// 220.185 us; speedup vs baseline: 2.3309x; 1.0293x over previous
//
#include <hip/hip_runtime.h>

// GraphRelativeError: rel = |pred-target|/(|target|+0.1); per-graph mean over
// SORTED segments (G=1024, ~16384 elems each); out = mean(graph_means)*1e4.
//
// R9 (third resubmit — R9/R10/R11 benches all died in infrastructure):
// R7/R8's MLP restructure was defeated by the register allocator (VGPR=28 —
// can't hold 8 float4 results; compiler re-serialized to ~2 outstanding
// loads). Evidence kernel is latency-bound: L3-hot replays (FETCH 0.5 MB)
// run at the same speed as HBM-cold ones. Fix: __launch_bounds__(256,4)
// (16 waves/CU -> 128 VGPR budget), EPB=8192/IT=8 -> 16 dwordx4 loads
// (16 KB/wave) issued back-to-back, sched_barrier pins the cluster.
// gre_starts: windowed binary search (13 probes vs 24), safe fallback.

#define EPSILON_F 0.1f
#define SCALE_F 10000.0f

constexpr int BLOCK = 256;
constexpr int EPB = 8192;              // elements per block
constexpr int IT = EPB / (BLOCK * 4);  // 8 float4 iters per thread
constexpr int G_CONST = 1024;

// batch storage may be int32 (jax default) or int64 (x64 mode). Probe: batch
// is sorted with max = G-1 != 0, so int32-view element [n-1] is 0 iff int64
// (odd index -> high word of an int64 element whose value < 2^31).
__device__ __forceinline__ int load_batch(const int* __restrict__ b32,
                                          long long idx, bool is64) {
  return b32[is64 ? (idx << 1) : idx];
}

// Also zeroes sums[] so no separate memset node is needed.
__global__ __launch_bounds__(BLOCK)
void gre_starts(const int* __restrict__ batch32, int n, int g,
                int* __restrict__ starts, float* __restrict__ sums) {
  const int t = blockIdx.x * BLOCK + threadIdx.x;
  if (t < g) sums[t] = 0.f;
  if (t > g) return;
  if (t == 0) { starts[0] = 0; return; }
  if (t == g) { starts[g] = n; return; }
  const bool is64 = (batch32[n - 1] == 0);
  // Expected start ~ t*n/g with binomial deviation ~sqrt(n/g) (~128 here).
  // Search a +/-4096 window; verify window brackets the answer, else fall
  // back to full range (correct for ANY sorted input).
  const long long c = (long long)t * n / g;
  long long lo = c - 4096, hi = c + 4096;
  if (lo < 0) lo = 0;
  if (hi > n) hi = n;
  // answer >= lo iff lo==0 or batch[lo-1] < t
  if (lo > 0 && !(load_batch(batch32, lo - 1, is64) < t)) { lo = 0; hi = n; }
  // answer <= hi iff hi==n or batch[hi] >= t
  else if (hi < n && !(load_batch(batch32, hi, is64) >= t)) { lo = 0; hi = n; }
  while (lo < hi) {
    long long mid = (lo + hi) >> 1;
    if (load_batch(batch32, mid, is64) < t) lo = mid + 1; else hi = mid;
  }
  starts[t] = (int)lo;
}

__global__ __launch_bounds__(BLOCK, 4)  // 4 blocks/CU = 16 waves/CU, VGPR<=128
void gre_main(const float* __restrict__ pred, const float* __restrict__ target,
              const int* __restrict__ batch32, int n,
              const int* __restrict__ starts, float* __restrict__ sums) {
  const int tid = threadIdx.x;
  const long long s = (long long)blockIdx.x * EPB;
  long long e = s + EPB;
  if (e > n) e = n;
  const bool is64 = (batch32[n - 1] == 0);
  // Issue batch loads FIRST: the branch below waits on these while the 16
  // data loads stay outstanding (vmcnt counts from oldest).
  const int b0 = load_batch(batch32, s, is64);
  const int b1 = load_batch(batch32, e - 1, is64);

  // ---- Load phase: 16 x global_load_dwordx4 back-to-back (16 KB/wave) ----
  float4 pv[IT], tv[IT];
  const bool full = (s + EPB <= (long long)n);
  if (full) {
    #pragma unroll
    for (int it = 0; it < IT; ++it) {
      const long long i4 = s + (long long)(it * BLOCK + tid) * 4;
      pv[it] = *reinterpret_cast<const float4*>(pred + i4);
      tv[it] = *reinterpret_cast<const float4*>(target + i4);
    }
  } else {
    #pragma unroll
    for (int it = 0; it < IT; ++it) {
      const long long i4 = s + (long long)(it * BLOCK + tid) * 4;
      float p[4] = {0.f, 0.f, 0.f, 0.f}, t[4] = {0.f, 0.f, 0.f, 0.f};
      #pragma unroll
      for (int j = 0; j < 4; ++j) {
        if (i4 + j < e) { p[j] = pred[i4 + j]; t[j] = target[i4 + j]; }
      }
      pv[it] = make_float4(p[0], p[1], p[2], p[3]);
      tv[it] = make_float4(t[0], t[1], t[2], t[3]);
      // zero-fill => rel = 0/(0+eps) = 0: harmless to any bin
    }
  }
  // Pin the load cluster: nothing sinks above / between the loads.
  __builtin_amdgcn_sched_barrier(0);

  // ---- Compute rel in-place (overwrite pv; tv dies -> VGPR peak ~96) ----
  #pragma unroll
  for (int it = 0; it < IT; ++it) {
    pv[it].x = fabsf(pv[it].x - tv[it].x) / (fabsf(tv[it].x) + EPSILON_F);
    pv[it].y = fabsf(pv[it].y - tv[it].y) / (fabsf(tv[it].y) + EPSILON_F);
    pv[it].z = fabsf(pv[it].z - tv[it].z) / (fabsf(tv[it].z) + EPSILON_F);
    pv[it].w = fabsf(pv[it].w - tv[it].w) / (fabsf(tv[it].w) + EPSILON_F);
  }

  // ---- Binning ----
  float A = 0.f, B = 0.f;
  if (b1 == b0) {
    float Bx = 0.f, By = 0.f;
    #pragma unroll
    for (int it = 0; it < IT; ++it) {
      Bx += pv[it].x + pv[it].z;
      By += pv[it].y + pv[it].w;
    }
    B = Bx + By;
  } else if (b1 == b0 + 1) {
    const long long p = (long long)starts[b1];  // one broadcast load
    #pragma unroll
    for (int it = 0; it < IT; ++it) {
      const long long i4 = s + (long long)(it * BLOCK + tid) * 4;
      A += (i4 + 0 < p) ? pv[it].x : 0.f;  B += (i4 + 0 < p) ? 0.f : pv[it].x;
      A += (i4 + 1 < p) ? pv[it].y : 0.f;  B += (i4 + 1 < p) ? 0.f : pv[it].y;
      A += (i4 + 2 < p) ? pv[it].z : 0.f;  B += (i4 + 2 < p) ? 0.f : pv[it].z;
      A += (i4 + 3 < p) ? pv[it].w : 0.f;  B += (i4 + 3 < p) ? 0.f : pv[it].w;
    }
  } else {
    // generic fallback (>=2 boundaries in 8192 elems: impossible for this
    // data, kept for correctness): per-element binning from registers
    #pragma unroll
    for (int it = 0; it < IT; ++it) {
      const long long i4 = s + (long long)(it * BLOCK + tid) * 4;
      const float rr[4] = {pv[it].x, pv[it].y, pv[it].z, pv[it].w};
      for (int j = 0; j < 4; ++j) {
        const long long i = i4 + j;
        if (i < e) {
          int gi = load_batch(batch32, i, is64);
          atomicAdd(&sums[gi], rr[j]);
        }
      }
    }
  }

  // per-wave reduction -> <=2 relaxed global atomics per wave (no fences!)
  #pragma unroll
  for (int off = 32; off > 0; off >>= 1) {
    A += __shfl_down(A, off, 64);
    B += __shfl_down(B, off, 64);
  }
  if ((tid & 63) == 0) {
    atomicAdd(&sums[b1], B);
    if (b1 != b0) atomicAdd(&sums[b0], A);
  }
}

__global__ __launch_bounds__(BLOCK)
void gre_final(const float* __restrict__ sums, const int* __restrict__ starts,
               float* __restrict__ out, int g) {
  const int tid = threadIdx.x;
  float v = 0.f;
  for (int i = tid; i < g; i += BLOCK)
    v += sums[i] / (float)(starts[i + 1] - starts[i]);
  #pragma unroll
  for (int off = 32; off > 0; off >>= 1) v += __shfl_down(v, off, 64);
  __shared__ float wsum[BLOCK / 64];
  if ((tid & 63) == 0) wsum[tid >> 6] = v;
  __syncthreads();
  if (tid == 0) {
    float t = 0.f;
    #pragma unroll
    for (int w = 0; w < BLOCK / 64; ++w) t += wsum[w];
    out[0] = (t / (float)g) * SCALE_F;
  }
}

extern "C" void kernel_launch(void* const* d_in, const int* in_sizes, int n_in,
                              void* d_out, int out_size, void* d_ws, size_t ws_size,
                              hipStream_t stream) {
  const float* pred   = (const float*)d_in[0];
  const float* target = (const float*)d_in[1];
  const int*   batch  = (const int*)d_in[2];  // int32 or int64, probed on device
  const int n = in_sizes[0];
  const int g = G_CONST;

  // ws layout: sums[1024] f32 | starts[1025] i32
  float* sums = (float*)d_ws;
  int* starts = (int*)((char*)d_ws + 4096);

  gre_starts<<<(g + BLOCK) / BLOCK, BLOCK, 0, stream>>>(batch, n, g, starts,
                                                        sums);
  const int nblocks = (n + EPB - 1) / EPB;
  gre_main<<<nblocks, BLOCK, 0, stream>>>(pred, target, batch, n, starts, sums);
  gre_final<<<1, BLOCK, 0, stream>>>(sums, starts, (float*)d_out, g);
}